// Round 1
// baseline (363.021 us; speedup 1.0000x reference)
//
#include <hip/hip_runtime.h>

#define HW 4096
#define GCAP 512u      // per-group candidate slots (expected ~100-200/group)
#define OCAP 65536u    // global overflow list (expected 0 used)

typedef short bf16x8 __attribute__((ext_vector_type(8)));
typedef float f32x16 __attribute__((ext_vector_type(16)));

__device__ __forceinline__ ushort f2bf_rne(float f) {
    unsigned u = __float_as_uint(f);
    return (ushort)((u + 0x7FFFu + ((u >> 16) & 1u)) >> 16);
}

// round toward +inf: stored bf16 >= exact f32.  (negative: truncation is
// toward zero = up; positive with dropped bits: bump.)
__device__ __forceinline__ ushort f2bf_up(float f) {
    unsigned u = __float_as_uint(f);
    ushort t = (ushort)(u >> 16);
    if (!(u & 0x80000000u) && (u & 0xFFFFu)) t += 1;
    return t;
}

// ---------------------------------------------------------------------------
// init: zero per-(b,n) best keys, per-group candidate counts, overflow count.
// ---------------------------------------------------------------------------
__global__ __launch_bounds__(256) void init_kernel(
    unsigned long long* __restrict__ best, unsigned* __restrict__ gcnt,
    unsigned* __restrict__ ocnt)
{
    int i = blockIdx.x * 256 + threadIdx.x;   // 16384
    best[i] = 0ull;
    if (i < 1024) gcnt[i] = 0u;
    if (i == 0) ocnt[0] = 0u;
}

// ---------------------------------------------------------------------------
// W transpose: Wt[c][o] = W[o][c].
// ---------------------------------------------------------------------------
__global__ __launch_bounds__(256) void transpose_w_kernel(
    const float* __restrict__ Wm, float* __restrict__ Wt)
{
    const int o = blockIdx.x;        // 128
    const int c = threadIdx.x;       // 256
    Wt[c * 128 + o] = Wm[o * 256 + c];
}

// ---------------------------------------------------------------------------
// Kernel 1: 1x1-conv projection as an LDS-tiled vector GEMM (unchanged).
// Outputs: Qt/Pt fp32 [b][n][128], qnorm, bf16 packs in 32x32x16 fragment
// order: PK[b][t32][ks][lt][j] = proj[c=ks*16+(lt>>5)*8+j][n=t32*32+(lt&31)].
// ---------------------------------------------------------------------------
__global__ __launch_bounds__(256) void proj_kernel(
    const float* __restrict__ Fq, const float* __restrict__ Fp,
    const float* __restrict__ Wt, const float* __restrict__ bias,
    float* __restrict__ Qt, float* __restrict__ Pt,
    ushort* __restrict__ Qpk, ushort* __restrict__ Ppk,
    float* __restrict__ qnorm)
{
    __shared__ float Ws[64][128];    // 32 KB: c-chunk x o
    __shared__ float Xs[64][64];     // 16 KB: c-chunk x n
    __shared__ float psum[16][68];   // padded norm partials

    const int tid = threadIdx.x;
    const int z  = blockIdx.z;                 // 0: q, 1: p
    const float* __restrict__ X = z ? Fp : Fq;
    const int b  = blockIdx.y;
    const int n0 = blockIdx.x * 64;
    const int og = tid >> 4;                   // 0..15 -> o = og*8 .. +8
    const int ng = tid & 15;                   // 0..15 -> n = n0+ng*4 .. +4

    float acc[4][8];                           // [n][o]
    #pragma unroll
    for (int i = 0; i < 4; ++i)
        #pragma unroll
        for (int j = 0; j < 8; ++j) acc[i][j] = 0.f;

    for (int cc = 0; cc < 4; ++cc) {
        __syncthreads();                       // protect prior chunk's reads
        {
            const float4* src = (const float4*)(Wt + (size_t)cc * 64 * 128);
            float4* dst = (float4*)Ws;
            #pragma unroll
            for (int it = 0; it < 8; ++it) dst[it * 256 + tid] = src[it * 256 + tid];
        }
        #pragma unroll
        for (int it = 0; it < 4; ++it) {
            int f = it * 256 + tid;
            int r = f >> 4, n4 = f & 15;
            *(float4*)&Xs[r][n4 * 4] =
                *(const float4*)&X[(size_t)(b * 256 + cc * 64 + r) * HW + n0 + n4 * 4];
        }
        __syncthreads();

        for (int r = 0; r < 64; ++r) {
            float4 w0 = *(const float4*)&Ws[r][og * 8];
            float4 w1 = *(const float4*)&Ws[r][og * 8 + 4];
            float4 xv = *(const float4*)&Xs[r][ng * 4];
            float wa[8] = {w0.x, w0.y, w0.z, w0.w, w1.x, w1.y, w1.z, w1.w};
            float xa[4] = {xv.x, xv.y, xv.z, xv.w};
            #pragma unroll
            for (int i = 0; i < 4; ++i)
                #pragma unroll
                for (int j = 0; j < 8; ++j)
                    acc[i][j] += wa[j] * xa[i];
        }
    }

    {
        float4 b0 = *(const float4*)&bias[og * 8];
        float4 b1 = *(const float4*)&bias[og * 8 + 4];
        float ba[8] = {b0.x, b0.y, b0.z, b0.w, b1.x, b1.y, b1.z, b1.w};
        #pragma unroll
        for (int i = 0; i < 4; ++i)
            #pragma unroll
            for (int j = 0; j < 8; ++j) acc[i][j] += ba[j];
    }

    #pragma unroll
    for (int i = 0; i < 4; ++i) {
        float s = 0.f;
        #pragma unroll
        for (int j = 0; j < 8; ++j) s += acc[i][j] * acc[i][j];
        psum[og][ng * 4 + i] = s;
    }
    __syncthreads();
    float tot[4];
    #pragma unroll
    for (int i = 0; i < 4; ++i) {
        float s = 0.f;
        #pragma unroll
        for (int g = 0; g < 16; ++g) s += psum[g][ng * 4 + i];
        tot[i] = s;
    }

    if (z) {   // normalize p over its 128 channels
        #pragma unroll
        for (int i = 0; i < 4; ++i) {
            float s = 1.0f / sqrtf(tot[i]);
            #pragma unroll
            for (int j = 0; j < 8; ++j) acc[i][j] *= s;
        }
    } else if (og == 0) {
        #pragma unroll
        for (int i = 0; i < 4; ++i)
            qnorm[b * HW + n0 + ng * 4 + i] = sqrtf(tot[i]);
    }

    {
        float* __restrict__ T = z ? Pt : Qt;
        #pragma unroll
        for (int i = 0; i < 4; ++i) {
            size_t tb = ((size_t)b * HW + n0 + ng * 4 + i) * 128 + og * 8;
            *(float4*)&T[tb]     = make_float4(acc[i][0], acc[i][1], acc[i][2], acc[i][3]);
            *(float4*)&T[tb + 4] = make_float4(acc[i][4], acc[i][5], acc[i][6], acc[i][7]);
        }
    }
    {
        ushort* __restrict__ PK = z ? Ppk : Qpk;
        const int ks = og >> 1;
        #pragma unroll
        for (int i = 0; i < 4; ++i) {
            const int na  = n0 + ng * 4 + i;
            const int t32 = na >> 5;
            const int lt  = (na & 31) + 32 * (og & 1);
            ushort u[8];
            #pragma unroll
            for (int k = 0; k < 8; ++k) u[k] = f2bf_rne(acc[i][k]);
            size_t pk = ((((size_t)b * 128 + t32) * 8 + ks) * 64 + lt) * 8;
            uint4 w;
            w.x = (unsigned)u[0] | ((unsigned)u[1] << 16);
            w.y = (unsigned)u[2] | ((unsigned)u[3] << 16);
            w.z = (unsigned)u[4] | ((unsigned)u[5] << 16);
            w.w = (unsigned)u[6] | ((unsigned)u[7] << 16);
            *(uint4*)&PK[pk] = w;
        }
    }
}

// ---------------------------------------------------------------------------
// SINGLE sim pass: MFMA max AND 16:1 column-max sketch.
// D mapping (32x32x16): m = lane&31, n = (r&3)+8*(r>>2)+4*(lane>>5).
// A lane's 16 regs cover the 16 n's of one fixed group (n bit2 == lane>>5),
// so colmax16 is a pure in-lane tree max.  Stored round-UP bf16 so the
// stored value >= exact MFMA colmax (no false skip in the scan).
// Cmax[b][g][m], g = (n>>5)*2 + ((n>>2)&1), 4x256x4096 = 8 MB.
// ---------------------------------------------------------------------------
__global__ __launch_bounds__(256, 2) void sim_max_kernel(
    const ushort* __restrict__ Qpk, const ushort* __restrict__ Ppk,
    float* __restrict__ Vmax, ushort* __restrict__ Cmax)
{
    __shared__ ushort Qs[16384];
    __shared__ ushort Bs[16384];

    const int tid  = threadIdx.x;
    const int lane = tid & 63;
    const int w    = tid >> 6;
    const int nb   = blockIdx.x;
    const int b    = blockIdx.y;
    const int ms   = blockIdx.z;

    {
        const uint4* src = (const uint4*)(Qpk + ((size_t)b * 128 + nb * 4) * 4096);
        uint4* dst = (uint4*)Qs;
        #pragma unroll
        for (int it = 0; it < 8; ++it) dst[it * 256 + tid] = src[it * 256 + tid];
    }

    // this lane's Cmax row: g = (nb*4+w)*2 + (lane>>5)
    const size_t crow = ((size_t)b * 256 + (size_t)(nb * 4 + w) * 2 + (lane >> 5)) * 4096;
    const int mb0 = ms * 1024 + (lane & 31);

    float bestv[16];
    #pragma unroll
    for (int r = 0; r < 16; ++r) bestv[r] = -1e30f;

    for (int ch = 0; ch < 8; ++ch) {
        __syncthreads();
        {
            const uint4* src = (const uint4*)(Ppk +
                ((size_t)b * 128 + ms * 32 + ch * 4) * 4096);
            uint4* dst = (uint4*)Bs;
            #pragma unroll
            for (int it = 0; it < 8; ++it) dst[it * 256 + tid] = src[it * 256 + tid];
        }
        __syncthreads();

        for (int mtl = 0; mtl < 4; ++mtl) {
            f32x16 acc;
            #pragma unroll
            for (int r = 0; r < 16; ++r) acc[r] = 0.f;
            #pragma unroll
            for (int ks = 0; ks < 8; ++ks) {
                bf16x8 a  = *(const bf16x8*)&Qs[((w   * 8 + ks) * 64 + lane) * 8];
                bf16x8 bb = *(const bf16x8*)&Bs[((mtl * 8 + ks) * 64 + lane) * 8];
                acc = __builtin_amdgcn_mfma_f32_32x32x16_bf16(a, bb, acc, 0, 0, 0);
            }
            #pragma unroll
            for (int r = 0; r < 16; ++r)
                bestv[r] = fmaxf(bestv[r], acc[r]);

            // in-lane column-max over the 16 n's (tree, 15 fmax)
            float c0 = fmaxf(fmaxf(fmaxf(acc[0], acc[1]), fmaxf(acc[2], acc[3])),
                             fmaxf(fmaxf(acc[4], acc[5]), fmaxf(acc[6], acc[7])));
            float c1 = fmaxf(fmaxf(fmaxf(acc[8], acc[9]), fmaxf(acc[10], acc[11])),
                             fmaxf(fmaxf(acc[12], acc[13]), fmaxf(acc[14], acc[15])));
            Cmax[crow + mb0 + ch * 128 + mtl * 32] = f2bf_up(fmaxf(c0, c1));
        }
    }

    #pragma unroll
    for (int r = 0; r < 16; ++r) {
        float v = bestv[r];
        #pragma unroll
        for (int d = 1; d < 32; d <<= 1)
            v = fmaxf(v, __shfl_xor(v, d, 64));
        if ((lane & 31) == 0) {
            int nl_ = (r & 3) + 8 * (r >> 2) + 4 * (lane >> 5);
            int na = nb * 128 + w * 32 + nl_;
            Vmax[((size_t)b * HW + na) * 4 + ms] = v;
        }
    }
}

// ---------------------------------------------------------------------------
// threshold: thr[n] = max_s Vmax[n][s] - (0.016*||q_n|| + 1e-6)
// plus per-16n-group min: gmin[flatg], flatg = blockIdx*16 + tile*2 + gs.
// Group membership matches the lane mapping: n with (n>>2)&1 == gs in tile.
// ---------------------------------------------------------------------------
__global__ __launch_bounds__(256) void thresh_kernel(
    const float* __restrict__ Vmax, const float* __restrict__ qnorm,
    float* __restrict__ thr, float* __restrict__ gmin)
{
    __shared__ float red[256];
    const int tid = threadIdx.x;
    int i = blockIdx.x * 256 + tid;   // 16384
    float g = -1e30f;
    #pragma unroll
    for (int s = 0; s < 4; ++s) g = fmaxf(g, Vmax[(size_t)i * 4 + s]);
    float t = g - (0.016f * qnorm[i] + 1e-6f);
    thr[i] = t;
    red[tid] = t;
    __syncthreads();
    if (tid < 16) {
        int tile = tid >> 1, gs = tid & 1;
        float mn = 1e30f;
        #pragma unroll
        for (int j = 0; j < 16; ++j) {
            int nl = (j & 3) + 8 * (j >> 2) + 4 * gs;
            mn = fminf(mn, red[tile * 32 + nl]);
        }
        gmin[blockIdx.x * 16 + tid] = mn;
    }
}

// ---------------------------------------------------------------------------
// scan: VALU-only replacement for the old MFMA re-compute pass.  One block
// per (b,g) row of Cmax (8 KB); survivor m's (colmax16 >= gmin) go straight
// to this row's exclusive cand2 region; beyond GCAP spill to global overflow.
// ---------------------------------------------------------------------------
__global__ __launch_bounds__(256) void scan_kernel(
    const ushort* __restrict__ Cmax, const float* __restrict__ gmin,
    unsigned* __restrict__ cand2, unsigned* __restrict__ gcnt,
    unsigned* __restrict__ ocand, unsigned* __restrict__ ocnt)
{
    __shared__ unsigned lcnt;
    const int fg = blockIdx.x;        // 1024
    const int tid = threadIdx.x;
    if (tid == 0) lcnt = 0u;
    __syncthreads();

    const float gm = gmin[fg];
    const ushort* __restrict__ row = Cmax + (size_t)fg * 4096;

    #pragma unroll
    for (int it = 0; it < 4; ++it) {
        int m0 = (it * 256 + tid) * 4;
        uint2 v = *(const uint2*)&row[m0];
        unsigned wv[2] = {v.x, v.y};
        #pragma unroll
        for (int h = 0; h < 2; ++h) {
            float f0 = __uint_as_float((wv[h] & 0xFFFFu) << 16);
            float f1 = __uint_as_float(wv[h] & 0xFFFF0000u);
            #pragma unroll
            for (int q = 0; q < 2; ++q) {
                float f = q ? f1 : f0;
                if (f >= gm) {
                    unsigned m = (unsigned)(m0 + h * 2 + q);
                    unsigned pos = atomicAdd(&lcnt, 1u);
                    if (pos < GCAP) {
                        cand2[(size_t)fg * GCAP + pos] = m;
                    } else {
                        unsigned op = atomicAdd(ocnt, 1u);
                        if (op < OCAP) ocand[op] = ((unsigned)fg << 12) | m;
                    }
                }
            }
        }
    }

    __syncthreads();
    if (tid == 0) gcnt[fg] = lcnt < GCAP ? lcnt : GCAP;
}

// ---------------------------------------------------------------------------
// exact fp32 rescore, grouped: block fg stages its 16 q-rows in LDS (padded
// [16][132] -> only free 2-way bank aliasing), dots each survivor m against
// all 16 n, and gates atomicMax by acc >= thr[n] (the true fp32 argmax
// provably passes: acc(n,m*) >= Vmax_n - 0.00787||q|| > thr[n]).
// ---------------------------------------------------------------------------
__global__ __launch_bounds__(256) void rescore_kernel(
    const float* __restrict__ Qt, const float* __restrict__ Pt,
    const float* __restrict__ thr,
    const unsigned* __restrict__ cand2, const unsigned* __restrict__ gcnt,
    const unsigned* __restrict__ ocand, const unsigned* __restrict__ ocnt,
    unsigned long long* __restrict__ best)
{
    __shared__ float Qs[16][132];
    __shared__ float thr_s[16];
    __shared__ int nlist[16];

    const int fg = blockIdx.x;        // 1024
    const int tid = threadIdx.x;
    const int b = fg >> 8, g = fg & 255, t = g >> 1, gs = g & 1;

    if (tid < 16) {
        int n = t * 32 + (tid & 3) + 8 * (tid >> 2) + 4 * gs;
        nlist[tid] = n;
        thr_s[tid] = thr[b * HW + n];
    }
    __syncthreads();
    #pragma unroll
    for (int it = 0; it < 2; ++it) {
        int idx = it * 256 + tid;
        int row = idx >> 5, c4 = (idx & 31) * 4;
        *(float4*)&Qs[row][c4] =
            *(const float4*)&Qt[((size_t)b * HW + nlist[row]) * 128 + c4];
    }
    __syncthreads();

    unsigned cnt = gcnt[fg];
    for (unsigned p = tid; p < cnt * 16u; p += 256) {
        unsigned i = p >> 4, sub = p & 15;
        int m = (int)cand2[(size_t)fg * GCAP + i];
        const float4* __restrict__ pr = (const float4*)&Pt[((size_t)b * HW + m) * 128];
        float acc = 0.f;
        #pragma unroll
        for (int k = 0; k < 32; ++k) {
            float4 pv = pr[k];
            float4 qv = *(const float4*)&Qs[sub][k * 4];
            acc += qv.x * pv.x + qv.y * pv.y + qv.z * pv.z + qv.w * pv.w;
        }
        if (acc >= thr_s[sub]) {
            unsigned u = __float_as_uint(acc);
            unsigned kk = (u & 0x80000000u) ? ~u : (u | 0x80000000u);
            unsigned long long key = ((unsigned long long)kk << 32) | (unsigned)(4095 - m);
            atomicMax(&best[(size_t)b * HW + nlist[sub]], key);
        }
    }

    // overflow fallback (expected empty): ungated, grid-strided
    unsigned total = ocnt[0];
    if (total > OCAP) total = OCAP;
    for (unsigned i = blockIdx.x * 256 + tid; i < total; i += 1024 * 256) {
        unsigned e = ocand[i];
        unsigned fg2 = e >> 12, m = e & 4095u;
        int b2 = fg2 >> 8, g2 = fg2 & 255, t2 = g2 >> 1, gs2 = g2 & 1;
        const float* __restrict__ prow = &Pt[((size_t)b2 * HW + m) * 128];
        #pragma unroll 1
        for (int j = 0; j < 16; ++j) {
            int n = t2 * 32 + (j & 3) + 8 * (j >> 2) + 4 * gs2;
            const float* __restrict__ q = &Qt[((size_t)b2 * HW + n) * 128];
            float acc = 0.f;
            for (int k = 0; k < 128; ++k) acc += q[k] * prow[k];
            unsigned u = __float_as_uint(acc);
            unsigned kk = (u & 0x80000000u) ? ~u : (u | 0x80000000u);
            unsigned long long key = ((unsigned long long)kk << 32) | (unsigned)(4095 - m);
            atomicMax(&best[(size_t)b2 * HW + n], key);
        }
    }
}

// ---------------------------------------------------------------------------
// gather: out[b][c][n] = Fp[b][c][m(n)]; stage each 16 KB Fp row in LDS.
// ---------------------------------------------------------------------------
__global__ __launch_bounds__(256) void gather_kernel(
    const float* __restrict__ Fp, const unsigned long long* __restrict__ best,
    float* __restrict__ out)
{
    __shared__ float row[4096];
    const int blk = blockIdx.x;      // 1024 = 4b x 256c
    const int c = blk & 255;
    const int b = blk >> 8;
    const int tid = threadIdx.x;

    const float* __restrict__ src = Fp + ((size_t)b * 256 + c) * HW;
    #pragma unroll
    for (int it = 0; it < 4; ++it) {
        int f = it * 256 + tid;
        *(float4*)&row[f * 4] = *(const float4*)&src[f * 4];
    }
    __syncthreads();

    float* __restrict__ dst = out + ((size_t)b * 256 + c) * HW;
    #pragma unroll
    for (int it = 0; it < 16; ++it) {
        int n = it * 256 + tid;
        int m = 4095 - (int)(best[(size_t)b * HW + n] & 0xFFFull);
        dst[n] = row[m];
    }
}

extern "C" void kernel_launch(void* const* d_in, const int* in_sizes, int n_in,
                              void* d_out, int out_size, void* d_ws, size_t ws_size,
                              hipStream_t stream) {
    const float* Fq   = (const float*)d_in[0];
    const float* Fp   = (const float*)d_in[1];
    const float* Wm   = (const float*)d_in[2];
    const float* bias = (const float*)d_in[3];
    float* out = (float*)d_out;

    char* base = (char*)d_ws;
    float*  Qt    = (float*)(base);                               // 8 MB
    float*  Pt    = (float*)(base + (8u << 20));                  // 8 MB
    ushort* Qpk   = (ushort*)(base + (16u << 20));                // 4 MB
    ushort* Ppk   = (ushort*)(base + (20u << 20));                // 4 MB
    ushort* Cmax  = (ushort*)(base + (24u << 20));                // 8 MB
    char* x = base + (32u << 20);
    float*  qnorm = (float*)x;              x += 65536;           // 64 KB
    float*  Vmax  = (float*)x;              x += 262144;          // 256 KB
    float*  thr   = (float*)x;              x += 65536;           // 64 KB
    float*  gmin  = (float*)x;              x += 4096;            // 1024 f32
    unsigned long long* best = (unsigned long long*)x; x += 131072; // 128 KB
    unsigned* gcnt = (unsigned*)x;          x += 4096;            // 1024 u32
    unsigned* ocnt = (unsigned*)x;          x += 4096;
    unsigned* cand2 = (unsigned*)x;         x += (size_t)1024 * GCAP * 4; // 2 MB
    unsigned* ocand = (unsigned*)x;         x += OCAP * 4;        // 256 KB
    float*  Wtg   = (float*)x;                                    // 128 KB

    init_kernel<<<64, 256, 0, stream>>>(best, gcnt, ocnt);
    transpose_w_kernel<<<128, 256, 0, stream>>>(Wm, Wtg);
    proj_kernel<<<dim3(64, 4, 2), 256, 0, stream>>>(Fq, Fp, Wtg, bias,
                                                    Qt, Pt, Qpk, Ppk, qnorm);
    sim_max_kernel<<<dim3(32, 4, 4), 256, 0, stream>>>(Qpk, Ppk, Vmax, Cmax);
    thresh_kernel<<<64, 256, 0, stream>>>(Vmax, qnorm, thr, gmin);
    scan_kernel<<<1024, 256, 0, stream>>>(Cmax, gmin, cand2, gcnt, ocand, ocnt);
    rescore_kernel<<<1024, 256, 0, stream>>>(Qt, Pt, thr, cand2, gcnt,
                                             ocand, ocnt, best);
    gather_kernel<<<1024, 256, 0, stream>>>(Fp, best, out);
}

// Round 2
// 167.553 us; speedup vs baseline: 2.1666x; 2.1666x over previous
//
#include <hip/hip_runtime.h>

#define HW 4096
#define LCAP 1536      // per-block hit list (expected ~52/block)

typedef short bf16x8 __attribute__((ext_vector_type(8)));
typedef float f32x16 __attribute__((ext_vector_type(16)));

__device__ __forceinline__ ushort f2bf_rne(float f) {
    unsigned u = __float_as_uint(f);
    return (ushort)((u + 0x7FFFu + ((u >> 16) & 1u)) >> 16);
}

// ---------------------------------------------------------------------------
// init: zero per-(b,n) best keys.
// ---------------------------------------------------------------------------
__global__ __launch_bounds__(256) void init_kernel(
    unsigned long long* __restrict__ best)
{
    int i = blockIdx.x * 256 + threadIdx.x;   // 16384
    best[i] = 0ull;
}

// ---------------------------------------------------------------------------
// W transpose: Wt[c][o] = W[o][c].
// ---------------------------------------------------------------------------
__global__ __launch_bounds__(256) void transpose_w_kernel(
    const float* __restrict__ Wm, float* __restrict__ Wt)
{
    const int o = blockIdx.x;        // 128
    const int c = threadIdx.x;       // 256
    Wt[c * 128 + o] = Wm[o * 256 + c];
}

// ---------------------------------------------------------------------------
// Kernel 1: 1x1-conv projection as an LDS-tiled vector GEMM (unchanged).
// Outputs: Qt/Pt fp32 [b][n][128], qnorm, bf16 packs in 32x32x16 fragment
// order: PK[b][t32][ks][lt][j] = proj[c=ks*16+(lt>>5)*8+j][n=t32*32+(lt&31)].
// ---------------------------------------------------------------------------
__global__ __launch_bounds__(256) void proj_kernel(
    const float* __restrict__ Fq, const float* __restrict__ Fp,
    const float* __restrict__ Wt, const float* __restrict__ bias,
    float* __restrict__ Qt, float* __restrict__ Pt,
    ushort* __restrict__ Qpk, ushort* __restrict__ Ppk,
    float* __restrict__ qnorm)
{
    __shared__ float Ws[64][128];    // 32 KB: c-chunk x o
    __shared__ float Xs[64][64];     // 16 KB: c-chunk x n
    __shared__ float psum[16][68];   // padded norm partials

    const int tid = threadIdx.x;
    const int z  = blockIdx.z;                 // 0: q, 1: p
    const float* __restrict__ X = z ? Fp : Fq;
    const int b  = blockIdx.y;
    const int n0 = blockIdx.x * 64;
    const int og = tid >> 4;                   // 0..15 -> o = og*8 .. +8
    const int ng = tid & 15;                   // 0..15 -> n = n0+ng*4 .. +4

    float acc[4][8];                           // [n][o]
    #pragma unroll
    for (int i = 0; i < 4; ++i)
        #pragma unroll
        for (int j = 0; j < 8; ++j) acc[i][j] = 0.f;

    for (int cc = 0; cc < 4; ++cc) {
        __syncthreads();                       // protect prior chunk's reads
        {
            const float4* src = (const float4*)(Wt + (size_t)cc * 64 * 128);
            float4* dst = (float4*)Ws;
            #pragma unroll
            for (int it = 0; it < 8; ++it) dst[it * 256 + tid] = src[it * 256 + tid];
        }
        #pragma unroll
        for (int it = 0; it < 4; ++it) {
            int f = it * 256 + tid;
            int r = f >> 4, n4 = f & 15;
            *(float4*)&Xs[r][n4 * 4] =
                *(const float4*)&X[(size_t)(b * 256 + cc * 64 + r) * HW + n0 + n4 * 4];
        }
        __syncthreads();

        for (int r = 0; r < 64; ++r) {
            float4 w0 = *(const float4*)&Ws[r][og * 8];
            float4 w1 = *(const float4*)&Ws[r][og * 8 + 4];
            float4 xv = *(const float4*)&Xs[r][ng * 4];
            float wa[8] = {w0.x, w0.y, w0.z, w0.w, w1.x, w1.y, w1.z, w1.w};
            float xa[4] = {xv.x, xv.y, xv.z, xv.w};
            #pragma unroll
            for (int i = 0; i < 4; ++i)
                #pragma unroll
                for (int j = 0; j < 8; ++j)
                    acc[i][j] += wa[j] * xa[i];
        }
    }

    {
        float4 b0 = *(const float4*)&bias[og * 8];
        float4 b1 = *(const float4*)&bias[og * 8 + 4];
        float ba[8] = {b0.x, b0.y, b0.z, b0.w, b1.x, b1.y, b1.z, b1.w};
        #pragma unroll
        for (int i = 0; i < 4; ++i)
            #pragma unroll
            for (int j = 0; j < 8; ++j) acc[i][j] += ba[j];
    }

    #pragma unroll
    for (int i = 0; i < 4; ++i) {
        float s = 0.f;
        #pragma unroll
        for (int j = 0; j < 8; ++j) s += acc[i][j] * acc[i][j];
        psum[og][ng * 4 + i] = s;
    }
    __syncthreads();
    float tot[4];
    #pragma unroll
    for (int i = 0; i < 4; ++i) {
        float s = 0.f;
        #pragma unroll
        for (int g = 0; g < 16; ++g) s += psum[g][ng * 4 + i];
        tot[i] = s;
    }

    if (z) {   // normalize p over its 128 channels
        #pragma unroll
        for (int i = 0; i < 4; ++i) {
            float s = 1.0f / sqrtf(tot[i]);
            #pragma unroll
            for (int j = 0; j < 8; ++j) acc[i][j] *= s;
        }
    } else if (og == 0) {
        #pragma unroll
        for (int i = 0; i < 4; ++i)
            qnorm[b * HW + n0 + ng * 4 + i] = sqrtf(tot[i]);
    }

    {
        float* __restrict__ T = z ? Pt : Qt;
        #pragma unroll
        for (int i = 0; i < 4; ++i) {
            size_t tb = ((size_t)b * HW + n0 + ng * 4 + i) * 128 + og * 8;
            *(float4*)&T[tb]     = make_float4(acc[i][0], acc[i][1], acc[i][2], acc[i][3]);
            *(float4*)&T[tb + 4] = make_float4(acc[i][4], acc[i][5], acc[i][6], acc[i][7]);
        }
    }
    {
        ushort* __restrict__ PK = z ? Ppk : Qpk;
        const int ks = og >> 1;
        #pragma unroll
        for (int i = 0; i < 4; ++i) {
            const int na  = n0 + ng * 4 + i;
            const int t32 = na >> 5;
            const int lt  = (na & 31) + 32 * (og & 1);
            ushort u[8];
            #pragma unroll
            for (int k = 0; k < 8; ++k) u[k] = f2bf_rne(acc[i][k]);
            size_t pk = ((((size_t)b * 128 + t32) * 8 + ks) * 64 + lt) * 8;
            uint4 w;
            w.x = (unsigned)u[0] | ((unsigned)u[1] << 16);
            w.y = (unsigned)u[2] | ((unsigned)u[3] << 16);
            w.z = (unsigned)u[4] | ((unsigned)u[5] << 16);
            w.w = (unsigned)u[6] | ((unsigned)u[7] << 16);
            *(uint4*)&PK[pk] = w;
        }
    }
}

// ---------------------------------------------------------------------------
// SINGLE sim pass: exact per-n max (Vmax) AND per-n u8 sketch.
// D mapping (32x32x16): m = lane&31, n = (r&3)+8*(r>>2)+4*(lane>>5).
// Sketch SK[b][g16][m][j]: j = reg index r (16 n's of the lane's group),
// g16 = (nb*4+w)*2 + (lane>>5).  u8 = rne(s * 256/||q_n||), HW-clamped.
// Guarantee used by scan: s >= thr  =>  u8 >= t8[n]  (t8 has a -1 cushion
// covering RNE's -0.5 and fp rounding of the scale products).
// ---------------------------------------------------------------------------
__global__ __launch_bounds__(256, 2) void sim_sketch_kernel(
    const ushort* __restrict__ Qpk, const ushort* __restrict__ Ppk,
    const float* __restrict__ qnorm,
    float* __restrict__ Vmax, unsigned char* __restrict__ SK)
{
    __shared__ ushort Qs[16384];
    __shared__ ushort Bs[16384];

    const int tid  = threadIdx.x;
    const int lane = tid & 63;
    const int w    = tid >> 6;
    const int nb   = blockIdx.x;
    const int b    = blockIdx.y;
    const int ms   = blockIdx.z;
    const int hi   = lane >> 5;

    {
        const uint4* src = (const uint4*)(Qpk + ((size_t)b * 128 + nb * 4) * 4096);
        uint4* dst = (uint4*)Qs;
        #pragma unroll
        for (int it = 0; it < 8; ++it) dst[it * 256 + tid] = src[it * 256 + tid];
    }

    // per-n reciprocal scales for this lane's 16 n's (same 256/qn expression
    // as thresh_kernel -> bitwise-identical scale on both sides)
    float rq[16];
    #pragma unroll
    for (int r = 0; r < 16; ++r) {
        int nl_ = (r & 3) + 8 * (r >> 2) + 4 * hi;
        rq[r] = 256.0f / qnorm[b * HW + nb * 128 + w * 32 + nl_];
    }

    // flat group index for sketch rows
    const size_t g16f = (size_t)b * 256 + (size_t)(nb * 4 + w) * 2 + hi;
    const int mb0 = ms * 1024 + (lane & 31);

    float bestv[16];
    #pragma unroll
    for (int r = 0; r < 16; ++r) bestv[r] = -1e30f;

    for (int ch = 0; ch < 8; ++ch) {
        __syncthreads();
        {
            const uint4* src = (const uint4*)(Ppk +
                ((size_t)b * 128 + ms * 32 + ch * 4) * 4096);
            uint4* dst = (uint4*)Bs;
            #pragma unroll
            for (int it = 0; it < 8; ++it) dst[it * 256 + tid] = src[it * 256 + tid];
        }
        __syncthreads();

        for (int mtl = 0; mtl < 4; ++mtl) {
            f32x16 acc;
            #pragma unroll
            for (int r = 0; r < 16; ++r) acc[r] = 0.f;
            #pragma unroll
            for (int ks = 0; ks < 8; ++ks) {
                bf16x8 a  = *(const bf16x8*)&Qs[((w   * 8 + ks) * 64 + lane) * 8];
                bf16x8 bb = *(const bf16x8*)&Bs[((mtl * 8 + ks) * 64 + lane) * 8];
                acc = __builtin_amdgcn_mfma_f32_32x32x16_bf16(a, bb, acc, 0, 0, 0);
            }
            #pragma unroll
            for (int r = 0; r < 16; ++r)
                bestv[r] = fmaxf(bestv[r], acc[r]);

            // quantize the 16 n-values of this m into one uint4
            unsigned dw[4] = {0u, 0u, 0u, 0u};
            #pragma unroll
            for (int r = 0; r < 16; ++r) {
                float x = acc[r] * rq[r];
#if __has_builtin(__builtin_amdgcn_cvt_pk_u8_f32)
                dw[r >> 2] = (unsigned)__builtin_amdgcn_cvt_pk_u8_f32(
                    x, (unsigned)(r & 3), (int)dw[r >> 2]);
#else
                int vi = (int)rintf(x);
                vi = vi < 0 ? 0 : (vi > 255 ? 255 : vi);
                dw[r >> 2] |= (unsigned)vi << (8 * (r & 3));
#endif
            }
            const int m = mb0 + ch * 128 + mtl * 32;
            uint4 pk;
            pk.x = dw[0]; pk.y = dw[1]; pk.z = dw[2]; pk.w = dw[3];
            *(uint4*)(SK + ((g16f * 4096 + (size_t)m) << 4)) = pk;
        }
    }

    #pragma unroll
    for (int r = 0; r < 16; ++r) {
        float v = bestv[r];
        #pragma unroll
        for (int d = 1; d < 32; d <<= 1)
            v = fmaxf(v, __shfl_xor(v, d, 64));
        if ((lane & 31) == 0) {
            int nl_ = (r & 3) + 8 * (r >> 2) + 4 * hi;
            int na = nb * 128 + w * 32 + nl_;
            Vmax[((size_t)b * HW + na) * 4 + ms] = v;
        }
    }
}

// ---------------------------------------------------------------------------
// threshold -> u8 domain: thr = max_s Vmax - (0.016*||q||+1e-6);
// t8[n] = clamp(floor(thr*256/||q||) - 1, 0, 255), stored at [g16][j] so the
// scan can load its 16 thresholds as one uint4.
// ---------------------------------------------------------------------------
__global__ __launch_bounds__(256) void thresh_kernel(
    const float* __restrict__ Vmax, const float* __restrict__ qnorm,
    unsigned char* __restrict__ t8pk)
{
    int i = blockIdx.x * 256 + threadIdx.x;   // b*4096 + n
    float g = -1e30f;
    #pragma unroll
    for (int s = 0; s < 4; ++s) g = fmaxf(g, Vmax[(size_t)i * 4 + s]);
    float qn  = qnorm[i];
    float thr = g - (0.016f * qn + 1e-6f);
    float scl = 256.0f / qn;                  // same expression as sim pass
    int t = (int)floorf(thr * scl) - 1;
    t = t < 0 ? 0 : (t > 255 ? 255 : t);
    int b = i >> 12, n = i & 4095;
    int nl = n & 31;
    int j   = (nl & 3) + 4 * (nl >> 3);
    int g16 = (n >> 5) * 2 + ((nl >> 2) & 1);
    t8pk[(((size_t)b * 256 + g16) << 4) + j] = (unsigned char)t;
}

// ---------------------------------------------------------------------------
// fused scan + exact fp32 rescore.  One block per (b,g16): stream the 64 KB
// sketch row, byte-compare vs 16 thresholds, collect hits (j<<12|m) in LDS,
// then one exact dot per hit (16 q-rows staged in LDS).  No caps that can
// drop the argmax: LCAP overflow (never expected) falls back to inline dot.
// ---------------------------------------------------------------------------
__device__ __noinline__ void dot_one_slow(
    const float* Qsrow, const float* __restrict__ Pt,
    int b, int m, int n, unsigned long long* __restrict__ best)
{
    const float4* __restrict__ pr = (const float4*)&Pt[((size_t)b * HW + m) * 128];
    float acc = 0.f;
    #pragma unroll
    for (int k = 0; k < 32; ++k) {
        float4 pv = pr[k];
        float4 qv = *(const float4*)&Qsrow[k * 4];
        acc += qv.x * pv.x + qv.y * pv.y + qv.z * pv.z + qv.w * pv.w;
    }
    unsigned u = __float_as_uint(acc);
    unsigned kk = (u & 0x80000000u) ? ~u : (u | 0x80000000u);
    unsigned long long key = ((unsigned long long)kk << 32) | (unsigned)(4095 - m);
    atomicMax(&best[(size_t)b * HW + n], key);
}

__global__ __launch_bounds__(256) void scan_rescore_kernel(
    const unsigned char* __restrict__ SK, const unsigned char* __restrict__ t8pk,
    const float* __restrict__ Qt, const float* __restrict__ Pt,
    unsigned long long* __restrict__ best)
{
    __shared__ float Qs[16][132];
    __shared__ int nlist[16];
    __shared__ ushort hl[LCAP];
    __shared__ unsigned lcnt;

    const int fg  = blockIdx.x;               // b*256 + g16
    const int tid = threadIdx.x;
    const int b = fg >> 8, g = fg & 255, t = g >> 1, gs = g & 1;

    if (tid == 0) lcnt = 0u;
    if (tid < 16) {
        nlist[tid] = t * 32 + (tid & 3) + 8 * (tid >> 2) + 4 * gs;
    }
    __syncthreads();

    #pragma unroll
    for (int it = 0; it < 2; ++it) {
        int idx = it * 256 + tid;
        int row = idx >> 5, c4 = (idx & 31) * 4;
        *(float4*)&Qs[row][c4] =
            *(const float4*)&Qt[((size_t)b * HW + nlist[row]) * 128 + c4];
    }

    int myt[16];
    {
        uint4 tv = *(const uint4*)&t8pk[(size_t)fg << 4];
        unsigned ta[4] = {tv.x, tv.y, tv.z, tv.w};
        #pragma unroll
        for (int d = 0; d < 4; ++d)
            #pragma unroll
            for (int k = 0; k < 4; ++k)
                myt[d * 4 + k] = (int)((ta[d] >> (8 * k)) & 255u);
    }
    __syncthreads();

    const unsigned char* __restrict__ row = SK + ((size_t)fg << 16);
    for (int it = 0; it < 16; ++it) {
        const int m = it * 256 + tid;
        uint4 v = *(const uint4*)(row + ((size_t)m << 4));
        unsigned wv[4] = {v.x, v.y, v.z, v.w};
        #pragma unroll
        for (int d = 0; d < 4; ++d) {
            #pragma unroll
            for (int k = 0; k < 4; ++k) {
                int bv = (int)((wv[d] >> (8 * k)) & 255u);
                if (bv >= myt[d * 4 + k]) {
                    const int j = d * 4 + k;
                    unsigned pos = atomicAdd(&lcnt, 1u);
                    if (pos < LCAP) {
                        hl[pos] = (ushort)((j << 12) | m);
                    } else {   // overflow: handle inline (rare/never)
                        dot_one_slow(&Qs[j][0], Pt, b, m, nlist[j], best);
                    }
                }
            }
        }
    }

    __syncthreads();
    unsigned cnt = lcnt < LCAP ? lcnt : LCAP;
    for (unsigned p = tid; p < cnt; p += 256) {
        int e = hl[p];
        int j = e >> 12, m = e & 4095;
        const float4* __restrict__ pr = (const float4*)&Pt[((size_t)b * HW + m) * 128];
        float acc = 0.f;
        #pragma unroll
        for (int k = 0; k < 32; ++k) {
            float4 pv = pr[k];
            float4 qv = *(const float4*)&Qs[j][k * 4];
            acc += qv.x * pv.x + qv.y * pv.y + qv.z * pv.z + qv.w * pv.w;
        }
        unsigned u = __float_as_uint(acc);
        unsigned kk = (u & 0x80000000u) ? ~u : (u | 0x80000000u);
        unsigned long long key = ((unsigned long long)kk << 32) | (unsigned)(4095 - m);
        atomicMax(&best[(size_t)b * HW + nlist[j]], key);
    }
}

// ---------------------------------------------------------------------------
// gather: out[b][c][n] = Fp[b][c][m(n)]; stage each 16 KB Fp row in LDS.
// ---------------------------------------------------------------------------
__global__ __launch_bounds__(256) void gather_kernel(
    const float* __restrict__ Fp, const unsigned long long* __restrict__ best,
    float* __restrict__ out)
{
    __shared__ float row[4096];
    const int blk = blockIdx.x;      // 1024 = 4b x 256c
    const int c = blk & 255;
    const int b = blk >> 8;
    const int tid = threadIdx.x;

    const float* __restrict__ src = Fp + ((size_t)b * 256 + c) * HW;
    #pragma unroll
    for (int it = 0; it < 4; ++it) {
        int f = it * 256 + tid;
        *(float4*)&row[f * 4] = *(const float4*)&src[f * 4];
    }
    __syncthreads();

    float* __restrict__ dst = out + ((size_t)b * 256 + c) * HW;
    #pragma unroll
    for (int it = 0; it < 16; ++it) {
        int n = it * 256 + tid;
        int m = 4095 - (int)(best[(size_t)b * HW + n] & 0xFFFull);
        dst[n] = row[m];
    }
}

extern "C" void kernel_launch(void* const* d_in, const int* in_sizes, int n_in,
                              void* d_out, int out_size, void* d_ws, size_t ws_size,
                              hipStream_t stream) {
    const float* Fq   = (const float*)d_in[0];
    const float* Fp   = (const float*)d_in[1];
    const float* Wm   = (const float*)d_in[2];
    const float* bias = (const float*)d_in[3];
    float* out = (float*)d_out;

    char* base = (char*)d_ws;
    float*  Qt    = (float*)(base);                               // 8 MB
    float*  Pt    = (float*)(base + (8u << 20));                  // 8 MB
    ushort* Qpk   = (ushort*)(base + (16u << 20));                // 4 MB
    ushort* Ppk   = (ushort*)(base + (20u << 20));                // 4 MB
    unsigned char* SK = (unsigned char*)(base + (24u << 20));     // 64 MB
    char* x = base + (88u << 20);
    float*  qnorm = (float*)x;              x += 65536;           // 64 KB
    float*  Vmax  = (float*)x;              x += 262144;          // 256 KB
    unsigned char* t8pk = (unsigned char*)x; x += 16384;          // 16 KB
    unsigned long long* best = (unsigned long long*)x; x += 131072; // 128 KB
    float*  Wtg   = (float*)x;                                    // 128 KB

    init_kernel<<<64, 256, 0, stream>>>(best);
    transpose_w_kernel<<<128, 256, 0, stream>>>(Wm, Wtg);
    proj_kernel<<<dim3(64, 4, 2), 256, 0, stream>>>(Fq, Fp, Wtg, bias,
                                                    Qt, Pt, Qpk, Ppk, qnorm);
    sim_sketch_kernel<<<dim3(32, 4, 4), 256, 0, stream>>>(Qpk, Ppk, qnorm,
                                                          Vmax, SK);
    thresh_kernel<<<64, 256, 0, stream>>>(Vmax, qnorm, t8pk);
    scan_rescore_kernel<<<1024, 256, 0, stream>>>(SK, t8pk, Qt, Pt, best);
    gather_kernel<<<1024, 256, 0, stream>>>(Fp, best, out);
}